// Round 3
// baseline (243.381 us; speedup 1.0000x reference)
//
#include <hip/hip_runtime.h>
#include <hip/hip_bf16.h>
#include <cstdint>

// Problem: out = x @ (W + scale*B@A)^T + b
//   x[4,2048,2048] -> X[M=8192, K=2048],  W[N=2048, K=2048], b[N],
//   A[R=16, K], B[N, R=16], scale scalar.  ALL I/O IS FLOAT32.
// Internally: fold LoRA into W_eff, convert X/W_eff to bf16, one MFMA GEMM.

typedef __bf16 bf16x8 __attribute__((ext_vector_type(8)));
typedef float floatx4 __attribute__((ext_vector_type(4)));
typedef unsigned short ushort8 __attribute__((ext_vector_type(8)));

#define BM 128
#define BN 128
#define BK 32

__device__ __forceinline__ void gload_lds16(const void* g, void* l) {
    // 16B-per-lane async global->LDS. LDS dest must be wave-uniform base + lane*16.
    __builtin_amdgcn_global_load_lds((__attribute__((address_space(1))) void*)g,
                                     (__attribute__((address_space(3))) void*)l,
                                     16, 0, 0);
}

// fp32 -> bf16 bits, round-to-nearest-even (finite inputs only).
__device__ __forceinline__ unsigned short f2bf_bits(float f) {
    unsigned int u = __float_as_uint(f);
    u += 0x7FFFu + ((u >> 16) & 1u);
    return (unsigned short)(u >> 16);
}

// ---------------------------------------------------------------------------
// Kernel 1: fp32 -> bf16 convert (x).  8 elements/thread, vectorized.
// ---------------------------------------------------------------------------
__global__ __launch_bounds__(256)
void cvt_kernel(const float* __restrict__ in, unsigned short* __restrict__ out)
{
    size_t i = ((size_t)blockIdx.x * 256 + threadIdx.x) * 8;
    float4 a = *reinterpret_cast<const float4*>(in + i);
    float4 b = *reinterpret_cast<const float4*>(in + i + 4);
    ushort8 o;
    o[0] = f2bf_bits(a.x); o[1] = f2bf_bits(a.y);
    o[2] = f2bf_bits(a.z); o[3] = f2bf_bits(a.w);
    o[4] = f2bf_bits(b.x); o[5] = f2bf_bits(b.y);
    o[6] = f2bf_bits(b.z); o[7] = f2bf_bits(b.w);
    *reinterpret_cast<ushort8*>(out + i) = o;
}

// ---------------------------------------------------------------------------
// Kernel 2: W_eff[n][k] = W[n][k] + scale * sum_r B[n][r]*A[r][k], bf16 out.
// 256 threads per row n (2048/8 cols each), fp32 math.
// ---------------------------------------------------------------------------
__global__ __launch_bounds__(256)
void weff_kernel(const float* __restrict__ W,
                 const float* __restrict__ A,
                 const float* __restrict__ Bm,
                 const float* __restrict__ scale_p,
                 unsigned short* __restrict__ Weff)
{
    const int K = 2048, R = 16;
    int t  = blockIdx.x * 256 + threadIdx.x;
    int n  = t >> 8;
    int k8 = (t & 255) << 3;

    float s = *scale_p;

    float br[16];
#pragma unroll
    for (int r = 0; r < R; ++r)
        br[r] = s * Bm[n * R + r];

    float acc[8] = {0,0,0,0,0,0,0,0};
#pragma unroll
    for (int r = 0; r < R; ++r) {
        const float* ap = A + r * K + k8;
#pragma unroll
        for (int j = 0; j < 8; ++j)
            acc[j] += br[r] * ap[j];
    }

    const float* wp = W + (size_t)n * K + k8;
    ushort8 o;
#pragma unroll
    for (int j = 0; j < 8; ++j)
        o[j] = f2bf_bits(wp[j] + acc[j]);
    *reinterpret_cast<ushort8*>(Weff + (size_t)n * K + k8) = o;
}

// ---------------------------------------------------------------------------
// Kernel 3: out[M,N] (fp32) = Xbf[M,K] @ Weffbf[N,K]^T + bias (fp32)
// m97 structure: 128x128 tile, BK=32, 4 waves 2x2, 4x4 16x16x32 bf16 MFMAs.
// ---------------------------------------------------------------------------
__global__ __launch_bounds__(256)
void gemm_bias_kernel(const unsigned short* __restrict__ X,
                      const unsigned short* __restrict__ Wt,
                      const float* __restrict__ bias,
                      float* __restrict__ out)
{
    const int N = 2048, K = 2048;

    // Unpadded: global_load_lds needs lds_off == wave_base + lane*16.
    __shared__ alignas(16) unsigned short As[BM * BK];   // 8 KB
    __shared__ alignas(16) unsigned short Bs[BN * BK];   // 8 KB

    const int tid  = threadIdx.x;
    const int wave = tid >> 6;
    const int lane = tid & 63;
    const int bm = blockIdx.y * BM;
    const int bn = blockIdx.x * BN;

    // Staging: each thread loads 16B (8 bf16). row = tid/4, col-group = tid%4.
    const int srow = tid >> 2;
    const int scol = (tid & 3) << 3;

    const int wm   = (wave >> 1) << 6;  // 0 / 64
    const int wn   = (wave & 1) << 6;   // 0 / 64
    const int lrow = lane & 15;
    const int kgrp = (lane >> 4) << 3;  // 0,8,16,24

    floatx4 acc[4][4] = {};

    const unsigned short* gA = X  + (size_t)(bm + srow) * K + scol;
    const unsigned short* gB = Wt + (size_t)(bn + srow) * K + scol;
    unsigned short* lA = As + tid * 8;
    unsigned short* lB = Bs + tid * 8;

    for (int k0 = 0; k0 < K; k0 += BK) {
        gload_lds16(gA + k0,                  lA);
        gload_lds16(gA + (size_t)64 * K + k0, lA + 64 * BK);
        gload_lds16(gB + k0,                  lB);
        gload_lds16(gB + (size_t)64 * K + k0, lB + 64 * BK);
        __syncthreads();

        bf16x8 af[4], bf[4];
#pragma unroll
        for (int i = 0; i < 4; ++i)
            af[i] = *reinterpret_cast<const bf16x8*>(As + (wm + i * 16 + lrow) * BK + kgrp);
#pragma unroll
        for (int i = 0; i < 4; ++i)
            bf[i] = *reinterpret_cast<const bf16x8*>(Bs + (wn + i * 16 + lrow) * BK + kgrp);

#pragma unroll
        for (int mi = 0; mi < 4; ++mi)
#pragma unroll
            for (int ni = 0; ni < 4; ++ni)
                acc[mi][ni] = __builtin_amdgcn_mfma_f32_16x16x32_bf16(
                    af[mi], bf[ni], acc[mi][ni], 0, 0, 0);
        __syncthreads();
    }

    // Epilogue. C/D layout (m89/m91): col = lane&15, row = (lane>>4)*4 + reg.
    float bsv[4];
#pragma unroll
    for (int ni = 0; ni < 4; ++ni)
        bsv[ni] = bias[bn + wn + ni * 16 + lrow];

    const int rbase = (lane >> 4) << 2;
#pragma unroll
    for (int mi = 0; mi < 4; ++mi) {
#pragma unroll
        for (int r = 0; r < 4; ++r) {
            size_t rowoff = (size_t)(bm + wm + mi * 16 + rbase + r) * N;
#pragma unroll
            for (int ni = 0; ni < 4; ++ni)
                out[rowoff + bn + wn + ni * 16 + lrow] = acc[mi][ni][r] + bsv[ni];
        }
    }
}

extern "C" void kernel_launch(void* const* d_in, const int* in_sizes, int n_in,
                              void* d_out, int out_size, void* d_ws, size_t ws_size,
                              hipStream_t stream)
{
    const float* x  = (const float*)d_in[0];
    const float* W  = (const float*)d_in[1];
    const float* b  = (const float*)d_in[2];
    const float* A  = (const float*)d_in[3];
    const float* Bm = (const float*)d_in[4];
    const float* sc = (const float*)d_in[5];
    float* out = (float*)d_out;

    const size_t M = 8192, N = 2048, K = 2048;

    unsigned short* Xbf  = (unsigned short*)d_ws;                 // 32 MB
    unsigned short* Weff = (unsigned short*)d_ws + M * K;         // + 8 MB

    // 1) x fp32 -> bf16   (M*K = 16.7M elems, 8/thread)
    cvt_kernel<<<dim3(M * K / 8 / 256), dim3(256), 0, stream>>>(x, Xbf);

    // 2) fold LoRA: Weff = bf16(W + scale * B@A)
    weff_kernel<<<dim3(N * K / 8 / 256), dim3(256), 0, stream>>>(W, A, Bm, sc, Weff);

    // 3) out = Xbf @ Weff^T + b  (fp32 out)
    dim3 grid(N / BN, M / BM);
    gemm_bias_kernel<<<grid, dim3(256), 0, stream>>>(Xbf, Weff, b, out);
}

// Round 4
// 220.577 us; speedup vs baseline: 1.1034x; 1.1034x over previous
//
#include <hip/hip_runtime.h>
#include <hip/hip_bf16.h>
#include <cstdint>

// Problem: out = x @ (W + scale*B@A)^T + b
//   x[4,2048,2048] -> X[M=8192, K=2048],  W[N=2048, K=2048], b[N],
//   A[R=16, K], B[N, R=16], scale scalar.  ALL I/O IS FLOAT32.
// Pipeline: cvt x->bf16, fold LoRA into bf16 W_eff, one MFMA bias-GEMM.
// R4: BK=64 (32 MFMA/barrier, AITER ratio) + XOR bank swizzle in LDS.

typedef __bf16 bf16x8 __attribute__((ext_vector_type(8)));
typedef float floatx4 __attribute__((ext_vector_type(4)));
typedef unsigned short ushort8 __attribute__((ext_vector_type(8)));

#define BM 128
#define BN 128
#define BK 64

__device__ __forceinline__ void gload_lds16(const void* g, void* l) {
    // 16B-per-lane async global->LDS. LDS dest must be wave-uniform base + lane*16.
    __builtin_amdgcn_global_load_lds((__attribute__((address_space(1))) void*)g,
                                     (__attribute__((address_space(3))) void*)l,
                                     16, 0, 0);
}

// fp32 -> bf16 bits, round-to-nearest-even (finite inputs only).
__device__ __forceinline__ unsigned short f2bf_bits(float f) {
    unsigned int u = __float_as_uint(f);
    u += 0x7FFFu + ((u >> 16) & 1u);
    return (unsigned short)(u >> 16);
}

// ---------------------------------------------------------------------------
// Kernel 1: fp32 -> bf16 convert (x).  8 elements/thread, vectorized.
// ---------------------------------------------------------------------------
__global__ __launch_bounds__(256)
void cvt_kernel(const float* __restrict__ in, unsigned short* __restrict__ out)
{
    size_t i = ((size_t)blockIdx.x * 256 + threadIdx.x) * 8;
    float4 a = *reinterpret_cast<const float4*>(in + i);
    float4 b = *reinterpret_cast<const float4*>(in + i + 4);
    ushort8 o;
    o[0] = f2bf_bits(a.x); o[1] = f2bf_bits(a.y);
    o[2] = f2bf_bits(a.z); o[3] = f2bf_bits(a.w);
    o[4] = f2bf_bits(b.x); o[5] = f2bf_bits(b.y);
    o[6] = f2bf_bits(b.z); o[7] = f2bf_bits(b.w);
    *reinterpret_cast<ushort8*>(out + i) = o;
}

// ---------------------------------------------------------------------------
// Kernel 2: W_eff[n][k] = W[n][k] + scale * sum_r B[n][r]*A[r][k], bf16 out.
// ---------------------------------------------------------------------------
__global__ __launch_bounds__(256)
void weff_kernel(const float* __restrict__ W,
                 const float* __restrict__ A,
                 const float* __restrict__ Bm,
                 const float* __restrict__ scale_p,
                 unsigned short* __restrict__ Weff)
{
    const int K = 2048, R = 16;
    int t  = blockIdx.x * 256 + threadIdx.x;
    int n  = t >> 8;
    int k8 = (t & 255) << 3;

    float s = *scale_p;

    float br[16];
#pragma unroll
    for (int r = 0; r < R; ++r)
        br[r] = s * Bm[n * R + r];

    float acc[8] = {0,0,0,0,0,0,0,0};
#pragma unroll
    for (int r = 0; r < R; ++r) {
        const float* ap = A + r * K + k8;
#pragma unroll
        for (int j = 0; j < 8; ++j)
            acc[j] += br[r] * ap[j];
    }

    const float* wp = W + (size_t)n * K + k8;
    ushort8 o;
#pragma unroll
    for (int j = 0; j < 8; ++j)
        o[j] = f2bf_bits(wp[j] + acc[j]);
    *reinterpret_cast<ushort8*>(Weff + (size_t)n * K + k8) = o;
}

// ---------------------------------------------------------------------------
// Kernel 3: out[M,N] (fp32) = Xbf[M,K] @ Weffbf[N,K]^T + bias (fp32)
// 128x128 tile, BK=64, 4 waves 2x2, each wave 4x4 of 16x16x32 bf16 MFMA,
// 2 k-halves per tile => 32 MFMA per barrier.
// LDS layout (per tile): row r (128 B = 8 slots of 16 B); slot s of row r
// holds global col-group g = s ^ (r&7)  (XOR bank swizzle; writer picks the
// global source per lane, destination stays wave-uniform-base + lane*16).
// ---------------------------------------------------------------------------
__global__ __launch_bounds__(256)
void gemm_bias_kernel(const unsigned short* __restrict__ X,
                      const unsigned short* __restrict__ Wt,
                      const float* __restrict__ bias,
                      float* __restrict__ out)
{
    const int N = 2048, K = 2048;

    __shared__ alignas(16) unsigned short As[BM * BK];   // 16 KB
    __shared__ alignas(16) unsigned short Bs[BN * BK];   // 16 KB

    const int tid  = threadIdx.x;
    const int wave = tid >> 6;
    const int lane = tid & 63;
    const int bm = blockIdx.y * BM;
    const int bn = blockIdx.x * BN;

    // Staging: 64-col rows = 8 slots x 16B. Thread -> (row, slot).
    const int srow = tid >> 3;                       // 0..31 per round
    const int sslot = tid & 7;                       // LDS slot 0..7
    const int sgcol = (sslot ^ (srow & 7)) << 3;     // global col element (swizzled source)

    const int wm   = (wave >> 1) << 6;  // 0 / 64
    const int wn   = (wave & 1) << 6;   // 0 / 64
    const int lrow = lane & 15;
    const int quad = lane >> 4;         // 0..3

    floatx4 acc[4][4] = {};

    const unsigned short* gA = X  + (size_t)(bm + srow) * K + sgcol;
    const unsigned short* gB = Wt + (size_t)(bn + srow) * K + sgcol;
    unsigned short* lA = As + tid * 8;   // dest: wave-uniform base + lane*16B
    unsigned short* lB = Bs + tid * 8;

    for (int k0 = 0; k0 < K; k0 += BK) {
        // A tile: 128x64 bf16 = 16 KB = 4 rounds of 256 lanes x 16 B.
#pragma unroll
        for (int rd = 0; rd < 4; ++rd)
            gload_lds16(gA + (size_t)(rd * 32) * K + k0, lA + rd * 32 * BK);
#pragma unroll
        for (int rd = 0; rd < 4; ++rd)
            gload_lds16(gB + (size_t)(rd * 32) * K + k0, lB + rd * 32 * BK);
        __syncthreads();

#pragma unroll
        for (int h = 0; h < 2; ++h) {
            // col-group index cgi = h*4 + quad; row&7 == lane&7 for all frags.
            const int soff = ((h * 4 + quad) ^ (lane & 7)) << 3;  // swizzled slot offset (elems)
            bf16x8 af[4], bf[4];
#pragma unroll
            for (int i = 0; i < 4; ++i)
                af[i] = *reinterpret_cast<const bf16x8*>(As + (wm + i * 16 + lrow) * BK + soff);
#pragma unroll
            for (int i = 0; i < 4; ++i)
                bf[i] = *reinterpret_cast<const bf16x8*>(Bs + (wn + i * 16 + lrow) * BK + soff);

#pragma unroll
            for (int mi = 0; mi < 4; ++mi)
#pragma unroll
                for (int ni = 0; ni < 4; ++ni)
                    acc[mi][ni] = __builtin_amdgcn_mfma_f32_16x16x32_bf16(
                        af[mi], bf[ni], acc[mi][ni], 0, 0, 0);
        }
        __syncthreads();
    }

    // Epilogue. C/D layout (m89/m91): col = lane&15, row = (lane>>4)*4 + reg.
    float bsv[4];
#pragma unroll
    for (int ni = 0; ni < 4; ++ni)
        bsv[ni] = bias[bn + wn + ni * 16 + lrow];

    const int rbase = quad << 2;
#pragma unroll
    for (int mi = 0; mi < 4; ++mi) {
#pragma unroll
        for (int r = 0; r < 4; ++r) {
            size_t rowoff = (size_t)(bm + wm + mi * 16 + rbase + r) * N;
#pragma unroll
            for (int ni = 0; ni < 4; ++ni)
                out[rowoff + bn + wn + ni * 16 + lrow] = acc[mi][ni][r] + bsv[ni];
        }
    }
}

extern "C" void kernel_launch(void* const* d_in, const int* in_sizes, int n_in,
                              void* d_out, int out_size, void* d_ws, size_t ws_size,
                              hipStream_t stream)
{
    const float* x  = (const float*)d_in[0];
    const float* W  = (const float*)d_in[1];
    const float* b  = (const float*)d_in[2];
    const float* A  = (const float*)d_in[3];
    const float* Bm = (const float*)d_in[4];
    const float* sc = (const float*)d_in[5];
    float* out = (float*)d_out;

    const size_t M = 8192, N = 2048, K = 2048;

    unsigned short* Xbf  = (unsigned short*)d_ws;                 // 32 MB
    unsigned short* Weff = (unsigned short*)d_ws + M * K;         // + 8 MB

    // 1) x fp32 -> bf16
    cvt_kernel<<<dim3(M * K / 8 / 256), dim3(256), 0, stream>>>(x, Xbf);

    // 2) fold LoRA: Weff = bf16(W + scale * B@A)
    weff_kernel<<<dim3(N * K / 8 / 256), dim3(256), 0, stream>>>(W, A, Bm, sc, Weff);

    // 3) out = Xbf @ Weff^T + b  (fp32 out)
    dim3 grid(N / BN, M / BM);
    gemm_bias_kernel<<<grid, dim3(256), 0, stream>>>(Xbf, Weff, b, out);
}

// Round 5
// 216.707 us; speedup vs baseline: 1.1231x; 1.0179x over previous
//
#include <hip/hip_runtime.h>
#include <hip/hip_bf16.h>
#include <cstdint>

// Problem: out = x @ (W + scale*B@A)^T + b
//   x[4,2048,2048] -> X[M=8192, K=2048],  W[N=2048, K=2048], b[N],
//   A[R=16, K], B[N, R=16], scale scalar.  ALL I/O IS FLOAT32.
// Pipeline: fused (cvt x->bf16 + fold LoRA into bf16 W_eff), one MFMA GEMM.
// R4: BK=64 + XOR bank swizzle  -> 88.7 us GEMM, 0 bank conflicts.
// R5: XCD-rectangle block swizzle (L2 locality) + fused aux kernel.

typedef __bf16 bf16x8 __attribute__((ext_vector_type(8)));
typedef float floatx4 __attribute__((ext_vector_type(4)));
typedef unsigned short ushort8 __attribute__((ext_vector_type(8)));

#define BM 128
#define BN 128
#define BK 64

__device__ __forceinline__ void gload_lds16(const void* g, void* l) {
    // 16B-per-lane async global->LDS. LDS dest must be wave-uniform base + lane*16.
    __builtin_amdgcn_global_load_lds((__attribute__((address_space(1))) void*)g,
                                     (__attribute__((address_space(3))) void*)l,
                                     16, 0, 0);
}

// fp32 -> bf16 bits, round-to-nearest-even (finite inputs only).
__device__ __forceinline__ unsigned short f2bf_bits(float f) {
    unsigned int u = __float_as_uint(f);
    u += 0x7FFFu + ((u >> 16) & 1u);
    return (unsigned short)(u >> 16);
}

// ---------------------------------------------------------------------------
// Fused aux kernel.
//   blocks [0, 8192):      Xbf = bf16(x)         (8 elems/thread)
//   blocks [8192, 10240):  Weff = bf16(W + scale*B@A)
// Block-level divergence only; the two halves overlap on the device instead
// of serializing as two stream-ordered launches.
// ---------------------------------------------------------------------------
__global__ __launch_bounds__(256)
void aux_kernel(const float* __restrict__ x, unsigned short* __restrict__ Xbf,
                const float* __restrict__ W, const float* __restrict__ A,
                const float* __restrict__ Bm, const float* __restrict__ scale_p,
                unsigned short* __restrict__ Weff)
{
    const int K = 2048, R = 16;
    int bid = blockIdx.x;
    if (bid < 8192) {
        // ---- cvt x -> bf16 ----
        size_t i = ((size_t)bid * 256 + threadIdx.x) * 8;
        float4 a = *reinterpret_cast<const float4*>(x + i);
        float4 b = *reinterpret_cast<const float4*>(x + i + 4);
        ushort8 o;
        o[0] = f2bf_bits(a.x); o[1] = f2bf_bits(a.y);
        o[2] = f2bf_bits(a.z); o[3] = f2bf_bits(a.w);
        o[4] = f2bf_bits(b.x); o[5] = f2bf_bits(b.y);
        o[6] = f2bf_bits(b.z); o[7] = f2bf_bits(b.w);
        *reinterpret_cast<ushort8*>(Xbf + i) = o;
    } else {
        // ---- fold LoRA into W_eff ----
        int t  = (bid - 8192) * 256 + threadIdx.x;
        int n  = t >> 8;
        int k8 = (t & 255) << 3;

        float s = *scale_p;
        float br[16];
#pragma unroll
        for (int r = 0; r < R; ++r)
            br[r] = s * Bm[n * R + r];

        float acc[8] = {0,0,0,0,0,0,0,0};
#pragma unroll
        for (int r = 0; r < R; ++r) {
            const float* ap = A + r * K + k8;
#pragma unroll
            for (int j = 0; j < 8; ++j)
                acc[j] += br[r] * ap[j];
        }

        const float* wp = W + (size_t)n * K + k8;
        ushort8 o;
#pragma unroll
        for (int j = 0; j < 8; ++j)
            o[j] = f2bf_bits(wp[j] + acc[j]);
        *reinterpret_cast<ushort8*>(Weff + (size_t)n * K + k8) = o;
    }
}

// ---------------------------------------------------------------------------
// GEMM: out[M,N] (fp32) = Xbf[M,K] @ Weffbf[N,K]^T + bias (fp32)
// 128x128 tile, BK=64, 4 waves 2x2, 32 MFMA per barrier, XOR bank swizzle.
// 1-D grid 1024 with XCD-rectangle swizzle: assuming round-robin id%8 -> XCD,
// XCD k owns bm-stripes [8k, 8k+8) x all 16 bn  => per-XCD X footprint 4 MB
// (fits its L2) instead of the full 32 MB.
// ---------------------------------------------------------------------------
__global__ __launch_bounds__(256)
void gemm_bias_kernel(const unsigned short* __restrict__ X,
                      const unsigned short* __restrict__ Wt,
                      const float* __restrict__ bias,
                      float* __restrict__ out)
{
    const int N = 2048, K = 2048;

    __shared__ alignas(16) unsigned short As[BM * BK];   // 16 KB
    __shared__ alignas(16) unsigned short Bs[BN * BK];   // 16 KB

    const int tid  = threadIdx.x;
    const int wave = tid >> 6;
    const int lane = tid & 63;

    // XCD-rectangle swizzle (perf heuristic only; any mapping is correct).
    const int id  = blockIdx.x;          // 0..1023
    const int xcd = id & 7;
    const int s   = id >> 3;             // 0..127
    const int bm  = ((xcd << 3) | (s & 7)) * BM;   // 8 stripes per XCD
    const int bn  = (s >> 3) * BN;                 // all 16 n-tiles per XCD

    // Staging: 64-col rows = 8 slots x 16B. Thread -> (row, slot).
    const int srow  = tid >> 3;                      // 0..31 per round
    const int sslot = tid & 7;                       // LDS slot 0..7
    const int sgcol = (sslot ^ (srow & 7)) << 3;     // swizzled global col

    const int wm   = (wave >> 1) << 6;  // 0 / 64
    const int wn   = (wave & 1) << 6;   // 0 / 64
    const int lrow = lane & 15;
    const int quad = lane >> 4;         // 0..3

    floatx4 acc[4][4] = {};

    const unsigned short* gA = X  + (size_t)(bm + srow) * K + sgcol;
    const unsigned short* gB = Wt + (size_t)(bn + srow) * K + sgcol;
    unsigned short* lA = As + tid * 8;   // dest: wave-uniform base + lane*16B
    unsigned short* lB = Bs + tid * 8;

    for (int k0 = 0; k0 < K; k0 += BK) {
#pragma unroll
        for (int rd = 0; rd < 4; ++rd)
            gload_lds16(gA + (size_t)(rd * 32) * K + k0, lA + rd * 32 * BK);
#pragma unroll
        for (int rd = 0; rd < 4; ++rd)
            gload_lds16(gB + (size_t)(rd * 32) * K + k0, lB + rd * 32 * BK);
        __syncthreads();

#pragma unroll
        for (int h = 0; h < 2; ++h) {
            const int soff = ((h * 4 + quad) ^ (lane & 7)) << 3;  // swizzled slot
            bf16x8 af[4], bf[4];
#pragma unroll
            for (int i = 0; i < 4; ++i)
                af[i] = *reinterpret_cast<const bf16x8*>(As + (wm + i * 16 + lrow) * BK + soff);
#pragma unroll
            for (int i = 0; i < 4; ++i)
                bf[i] = *reinterpret_cast<const bf16x8*>(Bs + (wn + i * 16 + lrow) * BK + soff);

#pragma unroll
            for (int mi = 0; mi < 4; ++mi)
#pragma unroll
                for (int ni = 0; ni < 4; ++ni)
                    acc[mi][ni] = __builtin_amdgcn_mfma_f32_16x16x32_bf16(
                        af[mi], bf[ni], acc[mi][ni], 0, 0, 0);
        }
        __syncthreads();
    }

    // Epilogue. C/D layout (m89/m91): col = lane&15, row = (lane>>4)*4 + reg.
    float bsv[4];
#pragma unroll
    for (int ni = 0; ni < 4; ++ni)
        bsv[ni] = bias[bn + wn + ni * 16 + lrow];

    const int rbase = quad << 2;
#pragma unroll
    for (int mi = 0; mi < 4; ++mi) {
#pragma unroll
        for (int r = 0; r < 4; ++r) {
            size_t rowoff = (size_t)(bm + wm + mi * 16 + rbase + r) * N;
#pragma unroll
            for (int ni = 0; ni < 4; ++ni)
                out[rowoff + bn + wn + ni * 16 + lrow] = acc[mi][ni][r] + bsv[ni];
        }
    }
}

extern "C" void kernel_launch(void* const* d_in, const int* in_sizes, int n_in,
                              void* d_out, int out_size, void* d_ws, size_t ws_size,
                              hipStream_t stream)
{
    const float* x  = (const float*)d_in[0];
    const float* W  = (const float*)d_in[1];
    const float* b  = (const float*)d_in[2];
    const float* A  = (const float*)d_in[3];
    const float* Bm = (const float*)d_in[4];
    const float* sc = (const float*)d_in[5];
    float* out = (float*)d_out;

    const size_t M = 8192, N = 2048, K = 2048;

    unsigned short* Xbf  = (unsigned short*)d_ws;                 // 32 MB
    unsigned short* Weff = (unsigned short*)d_ws + M * K;         // + 8 MB

    // 1) fused: Xbf = bf16(x); Weff = bf16(W + scale * B@A)
    aux_kernel<<<dim3((M * K + N * K) / 8 / 256), dim3(256), 0, stream>>>(
        x, Xbf, W, A, Bm, sc, Weff);

    // 2) out = Xbf @ Weff^T + b  (fp32 out), XCD-swizzled 1-D grid
    gemm_bias_kernel<<<dim3((M / BM) * (N / BN)), dim3(256), 0, stream>>>(
        Xbf, Weff, b, out);
}